// Round 5
// baseline (6130.500 us; speedup 1.0000x reference)
//
#include <hip/hip_runtime.h>
#include <hip/hip_fp16.h>

// BiGRU persistent-kernel, round 8: R7 (out-staging, wave-granular arrive,
// dwordx4 poll, split MFMA chains) + ws_size guard with direct-out fallback.
// B=64, T=512, D=256, U=512. 128 persistent blocks = 2 dirs x 64 unit-slices.
//
// R7 post-mortem: container failed twice -- either infra flake (precedent in
// round 0) or ws overflow: R7 grew d_ws use 17.2MB -> 145MB (128MB stage)
// without checking ws_size. R8: kernel_launch branches on ws_size; if the
// stage fits, use staged path (owned-line stores + coalesced epilogue); else
// stage=nullptr -> direct out[] stores (verified R6 path, 5801us).
//
// Fetch theory (from R6 counters): FETCH 677MB = out[] RFO amplification
// (blocks s..s+3 share each 128B out-line, 32B chunks -> ~4x RFO = ~512MB)
// + x16 refetch ~134MB. Staged path removes the RFO term.

#define BB 64
#define TT 512
#define DD 256
#define UU 512
#define NBD 64        // blocks per direction
#define NJ 8          // units per block (NBD*NJ == UU)
#define LD3U (3*UU)

typedef _Float16 half8 __attribute__((ext_vector_type(8)));
typedef float floatx4 __attribute__((ext_vector_type(4)));
typedef unsigned uintx4 __attribute__((ext_vector_type(4)));
typedef unsigned long long u64;

union h8u { half8 h; u64 q[2]; };

// ---------------- setup: x -> fp16 [T][B][D]; zero h16 + barrier flags ------
__global__ void bigru_setup(const float* __restrict__ x, __half* __restrict__ x16,
                            __half* __restrict__ h16, unsigned* __restrict__ bars) {
    long idx = (long)blockIdx.x * blockDim.x + threadIdx.x;
    if (idx < (long)TT * BB * DD) {
        int t = (int)(idx / (BB * DD));
        int r = (int)(idx % (BB * DD));
        int b = r / DD;
        int d = r % DD;
        x16[idx] = __float2half(x[((long)b * TT + t) * DD + d]);
    }
    if (idx < 2 * 2 * BB * UU) h16[idx] = __float2half(0.0f);  // both parities, both dirs
    if (idx < 1024) bars[idx] = 0u;                            // both dirs' flag arrays
}

// ---- barrier halves (per-wave flags, no RMW) -------------------------------
__device__ __forceinline__ void bar_arrive_wave(unsigned* flags, int s, int wave,
                                                int lane, unsigned p) {
    // vmcnt is per-wave and FIFO: drains this wave's publishes (and its prior
    // fragment loads), then one flag store attests both.
    asm volatile("s_waitcnt vmcnt(0)" ::: "memory");
    if (lane == 0)
        __hip_atomic_store(&flags[s * 4 + wave], p, __ATOMIC_RELAXED,
                           __HIP_MEMORY_SCOPE_AGENT);
}

__device__ __forceinline__ void bar_wait(const unsigned* flags, unsigned p) {
    if (threadIdx.x < 64) {
        // Wave 0: lane l polls the 4 wave-flags of block s=l in ONE 16B
        // sc0 sc1 load (coherent, no L2 pollution). 1KB per round total.
        const unsigned* fp = flags + (threadIdx.x << 2);
        for (;;) {
            uintx4 f;
            asm volatile("global_load_dwordx4 %0, %1, off sc0 sc1\n\t"
                         "s_waitcnt vmcnt(0)"
                         : "=v"(f) : "v"(fp) : "memory");
            const bool ok = f.x >= p && f.y >= p && f.z >= p && f.w >= p;
            if (__ballot(!ok) == 0ull) break;
        }
    }
    __syncthreads();
}

// ---- coherent 16B fragment load: two relaxed agent u64 loads ---------------
__device__ __forceinline__ half8 ld_agent_frag(const __half* p) {
    h8u r;
    r.q[0] = __hip_atomic_load((const u64*)p,     __ATOMIC_RELAXED, __HIP_MEMORY_SCOPE_AGENT);
    r.q[1] = __hip_atomic_load((const u64*)p + 1, __ATOMIC_RELAXED, __HIP_MEMORY_SCOPE_AGENT);
    return r.h;
}

// ---------------- persistent BiGRU kernel -----------------------------------
__global__ __launch_bounds__(256, 1) void bigru_persistent(
    const __half* __restrict__ x16,
    const float* __restrict__ Wx_f, const float* __restrict__ Wh_f, const float* __restrict__ b_f,
    const float* __restrict__ Wx_b, const float* __restrict__ Wh_b, const float* __restrict__ b_b,
    __half* __restrict__ h16,    // [parity][dir][s][B][8] fp16, block-major
    __half* __restrict__ rh16,   // [dir][s][B][8] fp16, block-major
    unsigned* __restrict__ bars, // per-wave flags: dir0 [0..256), dir1 [256..512)
    float* __restrict__ stage,   // [t][dir*64+s][B][8] fp32, or nullptr
    float* __restrict__ out)     // [B][T][2U] fp32 (used when stage==nullptr)
{
    const int blk  = blockIdx.x;
    const int dir  = blk / NBD;          // 0 = forward, 1 = backward
    const int s    = blk % NBD;
    const int j0   = s * NJ;
    const int tid  = threadIdx.x;
    const int wave = tid >> 6;
    const int lane = tid & 63;
    const int n    = lane & 15;          // MFMA col (C-layout) / A-row (A-layout)
    const int quad = lane >> 4;
    const int mbase = wave * 16;         // this wave's batch-row tile
    const int arow  = mbase + n;         // row this lane loads for A-fragments
    const int koff  = quad * 8;          // k-offset within a K=32 fragment

    const float* Wx = dir ? Wx_b : Wx_f;
    const float* Wh = dir ? Wh_b : Wh_f;
    const float* bv = dir ? b_b  : b_f;

    // Per-wave LDS bounce tiles: transpose lane-scattered gate outputs into
    // row-contiguous chunks for coalesced full-line publishes.
    __shared__ __half lds_rh[4][16][8];   // 1KB: r*h fp16 per wave
    __shared__ __half lds_h[4][16][8];    // 1KB: h fp16 per wave
    __shared__ float  lds_out[4][16][8];  // 2KB: h fp32 for stage/out

    // ---- one-time: load weight fragments into registers (fp16) ----
    // Phase-A tile packs u-gate (cols 0..7 -> unit j0+n) and r-gate (cols 8..15).
    half8 WA[24];  // [x;h] @ W(:,u|r), K=768
    half8 W3[8];   // x @ Wx(:,c),      K=256 (cols n>=8 zero-padded)
    half8 WC[16];  // rh @ Wh(:,c),     K=512 (cols n>=8 zero-padded)
    const int colur = (n < 8) ? (j0 + n) : (UU + j0 + (n - 8));
#pragma unroll
    for (int f = 0; f < 24; ++f) {
        const int kb = f * 32 + koff;
#pragma unroll
        for (int kk = 0; kk < 8; ++kk) {
            const int k = kb + kk;
            float v = (k < DD) ? Wx[(long)k * LD3U + colur]
                               : Wh[(long)(k - DD) * LD3U + colur];
            WA[f][kk] = (_Float16)v;
        }
    }
#pragma unroll
    for (int f = 0; f < 8; ++f) {
        const int kb = f * 32 + koff;
#pragma unroll
        for (int kk = 0; kk < 8; ++kk) {
            float v = (n < 8) ? Wx[(long)(kb + kk) * LD3U + 2 * UU + j0 + n] : 0.0f;
            W3[f][kk] = (_Float16)v;
        }
    }
#pragma unroll
    for (int f = 0; f < 16; ++f) {
        const int kb = f * 32 + koff;
#pragma unroll
        for (int kk = 0; kk < 8; ++kk) {
            float v = (n < 8) ? Wh[(long)(kb + kk) * LD3U + 2 * UU + j0 + n] : 0.0f;
            WC[f][kk] = (_Float16)v;
        }
    }
    const float bias_ur = (n < 8) ? bv[j0 + n] : bv[UU + j0 + (n - 8)];
    const float bias_c  = (n < 8) ? bv[2 * UU + j0 + n] : 0.0f;

    // h slice owned by this lane (fp32): h[mbase+quad*4+i][j0+n] for n<8
    float h_own[4] = {0.f, 0.f, 0.f, 0.f};
    float u_keep[4] = {0.f, 0.f, 0.f, 0.f};

    unsigned* flags = bars + dir * 256;
    __half* rhb = rh16 + (long)dir * BB * UU;   // this dir's [s][B][8] region

    // Prologue: x fragments for t=0 + their h-independent MFMAs.
    floatx4 acc_ur = {0.f, 0.f, 0.f, 0.f};
    floatx4 acc_c  = {0.f, 0.f, 0.f, 0.f};
    {
        const int tx0 = dir ? (TT - 1) : 0;
        const __half* xrow = x16 + ((long)tx0 * BB + arow) * DD + koff;
        half8 axx[8];
#pragma unroll
        for (int f = 0; f < 8; ++f) axx[f] = *(const half8*)(xrow + f * 32);
#pragma unroll
        for (int f = 0; f < 8; ++f) {
            acc_ur = __builtin_amdgcn_mfma_f32_16x16x32_f16(axx[f], WA[f], acc_ur, 0, 0, 0);
            acc_c  = __builtin_amdgcn_mfma_f32_16x16x32_f16(axx[f], W3[f], acc_c, 0, 0, 0);
        }
    }

    for (int t = 0; t < TT; ++t) {
        // ---------------- Phase A (critical path: h-part only) ----------------
        // h block-major: fragment k-range f*32+quad*8..+8 lives at
        // half8 [(f*4+quad)*64 + arow]*8. Coherent loads (L2 may be stale).
        const __half* hin = h16 + (long)((t & 1) * 2 + dir) * BB * UU;
        half8 ah[16];
#pragma unroll
        for (int f = 0; f < 16; ++f)
            ah[f] = ld_agent_frag(hin + ((long)(f * 4 + quad) * BB + arow) * 8);
        // Two independent 8-MFMA chains (halved dependent latency), then add.
        floatx4 aur1 = {0.f, 0.f, 0.f, 0.f};
#pragma unroll
        for (int f = 0; f < 8; ++f) {
            acc_ur = __builtin_amdgcn_mfma_f32_16x16x32_f16(ah[f], WA[8 + f], acc_ur, 0, 0, 0);
            aur1   = __builtin_amdgcn_mfma_f32_16x16x32_f16(ah[8 + f], WA[16 + f], aur1, 0, 0, 0);
        }
        acc_ur = acc_ur + aur1;

        // gates: lane(quad,n) holds rows mbase+quad*4+i, col n
#pragma unroll
        for (int i = 0; i < 4; ++i) {
            const float pre = acc_ur[i] + bias_ur;
            const float sg = 1.0f / (1.0f + __expf(-pre));
            // r-lanes (n>=8) need h_own from lane-8 (same quad, col n-8)
            const int src = (n >= 8) ? (lane - 8) : lane;
            const float hov = __shfl(h_own[i], src);
            if (n >= 8) {
                lds_rh[wave][quad * 4 + i][n - 8] = __float2half(sg * hov);
            } else {
                u_keep[i] = sg;
            }
        }
        // In-wave transpose bounce -> one contiguous 256B publish per wave.
        asm volatile("s_waitcnt lgkmcnt(0)" ::: "memory");
        __builtin_amdgcn_sched_barrier(0);
        if (lane < 32) {
            const int r = lane >> 1, hh2 = lane & 1;
            const u64 v = *(const u64*)&lds_rh[wave][r][hh2 * 4];
            __hip_atomic_store((u64*)&rhb[((long)s * BB + mbase + r) * 8 + hh2 * 4], v,
                               __ATOMIC_RELAXED, __HIP_MEMORY_SCOPE_AGENT);
        }
        bar_arrive_wave(flags, s, wave, lane, 2u * (unsigned)t + 1u);

        // ---- overlap window 1: x(t+1) prefetch + h-independent MFMAs ----
        const bool last = (t == TT - 1);
        floatx4 nacc_ur = {0.f, 0.f, 0.f, 0.f};
        floatx4 nacc_c  = {0.f, 0.f, 0.f, 0.f};
        {
            const int tn = last ? t : (t + 1);
            const int txn = dir ? (TT - 1 - tn) : tn;
            const __half* xrow = x16 + ((long)txn * BB + arow) * DD + koff;
            half8 axx[8];
#pragma unroll
            for (int f = 0; f < 8; ++f) axx[f] = *(const half8*)(xrow + f * 32);
#pragma unroll
            for (int f = 0; f < 8; ++f) {
                nacc_ur = __builtin_amdgcn_mfma_f32_16x16x32_f16(axx[f], WA[f], nacc_ur, 0, 0, 0);
                nacc_c  = __builtin_amdgcn_mfma_f32_16x16x32_f16(axx[f], W3[f], nacc_c, 0, 0, 0);
            }
        }
        bar_wait(flags, 2u * (unsigned)t + 1u);

        // ---------------- Phase B ----------------
        half8 arh[16];
#pragma unroll
        for (int f = 0; f < 16; ++f)
            arh[f] = ld_agent_frag(rhb + ((long)(f * 4 + quad) * BB + arow) * 8);
        floatx4 ac1 = {0.f, 0.f, 0.f, 0.f};
#pragma unroll
        for (int f = 0; f < 8; ++f) {
            acc_c = __builtin_amdgcn_mfma_f32_16x16x32_f16(arh[f], WC[f], acc_c, 0, 0, 0);
            ac1   = __builtin_amdgcn_mfma_f32_16x16x32_f16(arh[8 + f], WC[8 + f], ac1, 0, 0, 0);
        }
        acc_c = acc_c + ac1;

        __half* hout = h16 + (long)(((t + 1) & 1) * 2 + dir) * BB * UU;
        if (n < 8) {
#pragma unroll
            for (int i = 0; i < 4; ++i) {
                float pre = acc_c[i] + bias_c;
                pre = fminf(fmaxf(pre, -15.0f), 15.0f);
                const float e2 = __expf(2.0f * pre);
                const float hh = (e2 - 1.0f) / (e2 + 1.0f);
                const float hn = (1.0f - u_keep[i]) * h_own[i] + u_keep[i] * hh;
                h_own[i] = hn;
                lds_h[wave][quad * 4 + i][n] = __float2half(hn);
                lds_out[wave][quad * 4 + i][n] = hn;
            }
        }
        asm volatile("s_waitcnt lgkmcnt(0)" ::: "memory");
        __builtin_amdgcn_sched_barrier(0);
        if (lane < 32) {
            const int r = lane >> 1, hh2 = lane & 1;
            const u64 v = *(const u64*)&lds_h[wave][r][hh2 * 4];
            __hip_atomic_store((u64*)&hout[((long)s * BB + mbase + r) * 8 + hh2 * 4], v,
                               __ATOMIC_RELAXED, __HIP_MEMORY_SCOPE_AGENT);
        }

        if (!last) bar_arrive_wave(flags, s, wave, lane, 2u * (unsigned)t + 2u);

        // ---- overlap window 2: output store ----
        if (lane < 32) {
            const int r = lane >> 1, hh2 = lane & 1;
            if (stage) {
                // Staged: owned lines, plain L2 writeback, no RFO sharing.
                float* stg = stage + ((long)(t * 128 + dir * 64 + s)) * 512;
                *(floatx4*)&stg[(mbase + r) * 8 + hh2 * 4]
                    = *(const floatx4*)&lds_out[wave][r][hh2 * 4];
            } else {
                // Fallback (R6 path): direct out write, 32B chunks.
                const int row = mbase + r;
                *(floatx4*)&out[((long)row * TT + t) * (2 * UU) + (long)dir * UU + j0 + hh2 * 4]
                    = *(const floatx4*)&lds_out[wave][r][hh2 * 4];
            }
        }
        acc_ur = nacc_ur;
        acc_c  = nacc_c;

        if (!last) bar_wait(flags, 2u * (unsigned)t + 2u);
    }
}

// ---------------- epilogue: stage [t][c][b][8] -> out [b][t][2U] ------------
__global__ void bigru_epilogue(const float* __restrict__ stage,
                               float* __restrict__ out) {
    const int tid  = threadIdx.x;
    const int pair = blockIdx.x * 2 + (tid >> 7);  // pair = t*B + b
    const int c    = tid & 127;                    // chunk = dir*64 + s
    const int b    = pair & (BB - 1);
    const int t    = pair >> 6;
    const float* p = stage + ((long)(t * 128 + c)) * 512 + b * 8;
    const floatx4 v0 = *(const floatx4*)p;
    const floatx4 v1 = *(const floatx4*)(p + 4);
    float* q = out + ((long)b * TT + t) * (2 * UU) + c * 8;
    *(floatx4*)q       = v0;
    *(floatx4*)(q + 4) = v1;
}

extern "C" void kernel_launch(void* const* d_in, const int* in_sizes, int n_in,
                              void* d_out, int out_size, void* d_ws, size_t ws_size,
                              hipStream_t stream) {
    const float* x    = (const float*)d_in[0];
    const float* Wx_f = (const float*)d_in[1];
    const float* Wh_f = (const float*)d_in[2];
    const float* b_f  = (const float*)d_in[3];
    const float* Wx_b = (const float*)d_in[4];
    const float* Wh_b = (const float*)d_in[5];
    const float* b_b  = (const float*)d_in[6];
    float* out = (float*)d_out;

    char* ws = (char*)d_ws;
    // ws layout: x16 16.78MB | h16 256KB | rh16 128KB | bars 4KB | stage 128MB?
    const size_t off_h16   = (size_t)TT * BB * DD * 2;
    const size_t off_rh16  = off_h16 + (size_t)2 * 2 * BB * UU * 2;
    const size_t off_bars  = off_rh16 + (size_t)2 * BB * UU * 2;
    const size_t off_stage = off_bars + 4096;
    const size_t stage_bytes = (size_t)TT * 128 * 512 * 4;  // 128 MiB

    __half* x16    = (__half*)ws;
    __half* h16    = (__half*)(ws + off_h16);
    __half* rh16   = (__half*)(ws + off_rh16);
    unsigned* bars = (unsigned*)(ws + off_bars);
    const bool staged = ws_size >= off_stage + stage_bytes;
    float* stage = staged ? (float*)(ws + off_stage) : (float*)nullptr;

    const long nsetup = (long)TT * BB * DD;  // 8.39M threads covers all init ranges
    bigru_setup<<<(int)((nsetup + 255) / 256), 256, 0, stream>>>(x, x16, h16, bars);
    bigru_persistent<<<2 * NBD, 256, 0, stream>>>(x16, Wx_f, Wh_f, b_f, Wx_b, Wh_b, b_b,
                                                  h16, rh16, bars, stage, out);
    if (staged)
        bigru_epilogue<<<(BB * TT) / 2, 256, 0, stream>>>(stage, out);
}

// Round 6
// 3608.504 us; speedup vs baseline: 1.6989x; 1.6989x over previous
//
#include <hip/hip_runtime.h>
#include <hip/hip_fp16.h>

// BiGRU persistent-kernel, round 9: 2-D decomposition (16 unit-slices x 4
// batch-groups per dir). B=64, T=512, D=256, U=512. 128 blocks total; sync
// domain = 16 blocks (dir,gb); each block owns M=16 batch rows x 32 units.
//
// R8 post-mortem: FETCH invariant to out staging -> out-RFO theory refuted;
// direct-out restored. Remaining 5.5us/phase = structural: every block read
// FULL h+rh (128KB/step) via IC, domain=64 blocks. R9: per-block exchange
// reads drop to 16KB h + 16KB rh per step (LDS-staged once, frag-read from
// LDS); aggregate 16MB -> 4MB/step; barrier width 64 -> 16 blocks.
// Protocol: monotonic per-wave flags; phase-A flags from rh-publishers
// (waves 2,3), phase-B flags from h-publishers (waves 0,1); vmcnt(0) FIFO
// drain before each flag attests that wave's stores AND prior reads, covering
// single-buffered rh reuse. h parity-double-buffered. Raw s_barrier + manual
// lgkmcnt so in-flight out-stores are not drained at barriers.

#define BB 64
#define TT 512
#define DD 256
#define UU 512
#define LD3U (3*UU)

typedef _Float16 half8 __attribute__((ext_vector_type(8)));
typedef float floatx4 __attribute__((ext_vector_type(4)));
typedef unsigned uintx4 __attribute__((ext_vector_type(4)));
typedef unsigned long long u64;

// ---------------- setup: x -> fp16 [T][B][D]; zero h16 + flags --------------
__global__ void bigru_setup(const float* __restrict__ x, __half* __restrict__ x16,
                            __half* __restrict__ h16, unsigned* __restrict__ bars) {
    long idx = (long)blockIdx.x * blockDim.x + threadIdx.x;
    if (idx < (long)TT * BB * DD) {
        int t = (int)(idx / (BB * DD));
        int r = (int)(idx % (BB * DD));
        int b = r / DD;
        int d = r % DD;
        x16[idx] = __float2half(x[((long)b * TT + t) * DD + d]);
    }
    if (idx < 2 * 2 * BB * UU) h16[idx] = __float2half(0.0f);  // 2 parities x 2 dirs
    if (idx < 1024) bars[idx] = 0u;                            // 8 domains x 128 words
}

// ---- coherent 16B load (bypass L1/L2, read coherence point) ----------------
__device__ __forceinline__ uintx4 ld16c(const void* p) {
    uintx4 v;
    asm volatile("global_load_dwordx4 %0, %1, off sc0 sc1" : "=v"(v) : "v"(p));
    return v;
}

__device__ __forceinline__ void barrier_lgkm() {
    asm volatile("s_waitcnt lgkmcnt(0)" ::: "memory");
    __builtin_amdgcn_sched_barrier(0);
    __builtin_amdgcn_s_barrier();
    __builtin_amdgcn_sched_barrier(0);
}

// ---- barrier wait: wave0 polls 32 flags (one dword sc0 sc1 per lane) -------
__device__ __forceinline__ void bar_wait(const unsigned* flags, int base, unsigned p) {
    if (threadIdx.x < 64) {
        const unsigned* fp = flags + base + (threadIdx.x & 31);
        for (;;) {
            unsigned v;
            asm volatile("global_load_dword %0, %1, off sc0 sc1\n\t"
                         "s_waitcnt vmcnt(0)"
                         : "=v"(v) : "v"(fp) : "memory");
            if (__ballot(v < p) == 0ull) break;
        }
    }
    __builtin_amdgcn_sched_barrier(0);
    __builtin_amdgcn_s_barrier();
    __builtin_amdgcn_sched_barrier(0);
}

// ---------------- persistent BiGRU kernel -----------------------------------
__global__ __launch_bounds__(256, 1) void bigru_persistent(
    const __half* __restrict__ x16,
    const float* __restrict__ Wx_f, const float* __restrict__ Wh_f, const float* __restrict__ b_f,
    const float* __restrict__ Wx_b, const float* __restrict__ Wh_b, const float* __restrict__ b_b,
    __half* __restrict__ h16,    // [parity][dir][gb][kc64][b16][8] fp16 (16KB/region)
    __half* __restrict__ rh16,   // [dir][gb][kc64][b16][8] fp16
    unsigned* __restrict__ bars, // 8 domains x 128 words; [0..32)=B-flags, [32..64)=A-flags
    float* __restrict__ out)     // [B][T][2U] fp32
{
    const int blk  = blockIdx.x;
    const int dir  = blk >> 6;
    const int gb   = (blk >> 4) & 3;     // batch group (16 rows)
    const int sb   = blk & 15;           // unit slice (32 units)
    const int dom  = dir * 4 + gb;
    const int tid  = threadIdx.x;
    const int wave = tid >> 6;
    const int lane = tid & 63;
    const int n    = lane & 15;          // MFMA col / A-row
    const int quad = lane >> 4;
    const int koff = quad * 8;
    const int j0   = sb * 32;            // unit base
    const int b0   = gb * 16;            // batch base

    const float* Wx = dir ? Wx_b : Wx_f;
    const float* Wh = dir ? Wh_b : Wh_f;
    const float* bv = dir ? b_b  : b_f;

    __shared__ __half lds_hst[64 * 16 * 8];   // 16KB staged h(t)
    __shared__ __half lds_rst[64 * 16 * 8];   // 16KB staged rh(t)
    __shared__ __half lds_hprev[16][32];      // 1KB  h(t) local slice (for r*h)
    __shared__ __half lds_rhb[16][32];        // 1KB  r*h bounce
    __shared__ float  lds_out[16][32];        // 2KB  h fp32 for out

    // ---- weights ----
    // waves 0,1: u cols; waves 2,3: r cols. N=16 per wave.
    const int colur = (wave < 2 ? 0 : UU) + j0 + (wave & 1) * 16 + n;
    half8 WA[24];   // [x;h] @ W(:,u|r) col tile, K=768
#pragma unroll
    for (int f = 0; f < 8; ++f)
#pragma unroll
        for (int kk = 0; kk < 8; ++kk)
            WA[f][kk] = (_Float16)Wx[(long)(f * 32 + koff + kk) * LD3U + colur];
#pragma unroll
    for (int f = 8; f < 24; ++f)
#pragma unroll
        for (int kk = 0; kk < 8; ++kk)
            WA[f][kk] = (_Float16)Wh[(long)((f - 8) * 32 + koff + kk) * LD3U + colur];
    const float bias_ur = bv[colur];

    half8 W3[8];    // x @ Wx(:,c)  (waves 0,1)
    half8 WC[16];   // rh @ Wh(:,c) (waves 0,1)
    const int colc = 2 * UU + j0 + (wave & 1) * 16 + n;
    float bias_c = 0.0f;
    if (wave < 2) {
#pragma unroll
        for (int f = 0; f < 8; ++f)
#pragma unroll
            for (int kk = 0; kk < 8; ++kk)
                W3[f][kk] = (_Float16)Wx[(long)(f * 32 + koff + kk) * LD3U + colc];
#pragma unroll
        for (int f = 0; f < 16; ++f)
#pragma unroll
            for (int kk = 0; kk < 8; ++kk)
                WC[f][kk] = (_Float16)Wh[(long)(f * 32 + koff + kk) * LD3U + colc];
        bias_c = bv[colc];
    } else {
#pragma unroll
        for (int f = 0; f < 8; ++f) W3[f] = (half8)(_Float16)0.0f;
#pragma unroll
        for (int f = 0; f < 16; ++f) WC[f] = (half8)(_Float16)0.0f;
    }

    float h_own[4]  = {0.f, 0.f, 0.f, 0.f};   // waves 0,1: h[b=quad*4+i][wave*16+n]
    float u_keep[4] = {0.f, 0.f, 0.f, 0.f};

    unsigned* flags = bars + dom * 128;
    __half* rhb = rh16 + (long)dom * 8192;

    // zero lds_hprev for t=0 r*h
    if (tid < 128) ((u64*)lds_hprev)[tid] = 0ull;

    // Prologue: x(0) frags + u/r x-part MFMAs.
    floatx4 acc_ur = {0.f, 0.f, 0.f, 0.f};
    floatx4 acc_c  = {0.f, 0.f, 0.f, 0.f};
    half8 axx[8];
    {
        const int tx0 = dir ? (TT - 1) : 0;
        const __half* xr = x16 + ((long)tx0 * BB + b0 + n) * DD + koff;
#pragma unroll
        for (int f = 0; f < 8; ++f) axx[f] = *(const half8*)(xr + f * 32);
#pragma unroll
        for (int f = 0; f < 8; ++f)
            acc_ur = __builtin_amdgcn_mfma_f32_16x16x32_f16(axx[f], WA[f], acc_ur, 0, 0, 0);
    }
    __syncthreads();

    for (int t = 0; t < TT; ++t) {
        const int p = t & 1;
        // ---------------- Phase A ----------------
        // stage h(t) -> LDS (all 256 threads, 4x16B each) + out(t-1) stores
        const __half* hsrc = h16 + ((long)(p * 2 + dir) * 4 + gb) * 8192;
        uintx4 st0 = ld16c(hsrc + (0 * 256 + tid) * 8);
        uintx4 st1 = ld16c(hsrc + (1 * 256 + tid) * 8);
        uintx4 st2 = ld16c(hsrc + (2 * 256 + tid) * 8);
        uintx4 st3 = ld16c(hsrc + (3 * 256 + tid) * 8);
        if (t > 0 && tid < 128) {
            const int b = tid >> 3, cc = tid & 7;
            *(floatx4*)&out[((long)(b0 + b) * TT + (t - 1)) * (2 * UU) + dir * UU + j0 + cc * 4]
                = *(const floatx4*)&lds_out[b][cc * 4];
        }
        asm volatile("s_waitcnt vmcnt(0)" ::: "memory");
        __builtin_amdgcn_sched_barrier(0);
        *(uintx4*)&lds_hst[(0 * 256 + tid) * 8] = st0;
        *(uintx4*)&lds_hst[(1 * 256 + tid) * 8] = st1;
        *(uintx4*)&lds_hst[(2 * 256 + tid) * 8] = st2;
        *(uintx4*)&lds_hst[(3 * 256 + tid) * 8] = st3;
        barrier_lgkm();

        // h-part MFMAs: A-frag k=f*32+quad*8 -> lds [kc=f*4+quad][b=n][8]
        {
            floatx4 a1 = {0.f, 0.f, 0.f, 0.f};
            half8 ah[8];
#pragma unroll
            for (int f = 0; f < 8; ++f)
                ah[f] = *(const half8*)&lds_hst[((f * 4 + quad) * 16 + n) * 8];
#pragma unroll
            for (int f = 0; f < 8; ++f)
                acc_ur = __builtin_amdgcn_mfma_f32_16x16x32_f16(ah[f], WA[8 + f], acc_ur, 0, 0, 0);
#pragma unroll
            for (int f = 0; f < 8; ++f)
                ah[f] = *(const half8*)&lds_hst[(((8 + f) * 4 + quad) * 16 + n) * 8];
#pragma unroll
            for (int f = 0; f < 8; ++f)
                a1 = __builtin_amdgcn_mfma_f32_16x16x32_f16(ah[f], WA[16 + f], a1, 0, 0, 0);
            acc_ur = acc_ur + a1;
        }

        if (wave >= 2) {
            // r gate -> r*h -> publish (units (wave-2)*16+n of this block)
#pragma unroll
            for (int i = 0; i < 4; ++i) {
                const float r = 1.0f / (1.0f + __expf(-(acc_ur[i] + bias_ur)));
                const float hp = (float)lds_hprev[quad * 4 + i][(wave - 2) * 16 + n];
                lds_rhb[quad * 4 + i][(wave - 2) * 16 + n] = (__half)(r * hp);
            }
            asm volatile("s_waitcnt lgkmcnt(0)" ::: "memory");
            __builtin_amdgcn_sched_barrier(0);
            if (lane < 32) {
                const int kcl = lane >> 4, b = lane & 15;
                const u64* src = (const u64*)&lds_rhb[b][(wave - 2) * 16 + kcl * 8];
                u64* dst = (u64*)(rhb + ((long)(sb * 4 + (wave - 2) * 2 + kcl) * 16 + b) * 8);
                __hip_atomic_store(dst,     src[0], __ATOMIC_RELAXED, __HIP_MEMORY_SCOPE_AGENT);
                __hip_atomic_store(dst + 1, src[1], __ATOMIC_RELAXED, __HIP_MEMORY_SCOPE_AGENT);
            }
            asm volatile("s_waitcnt vmcnt(0)" ::: "memory");
            if (lane == 0)
                __hip_atomic_store(&flags[32 + sb * 2 + (wave - 2)], 2u * (unsigned)t + 1u,
                                   __ATOMIC_RELAXED, __HIP_MEMORY_SCOPE_AGENT);
        } else {
            // u gate + c-gate x-part (window work)
#pragma unroll
            for (int i = 0; i < 4; ++i)
                u_keep[i] = 1.0f / (1.0f + __expf(-(acc_ur[i] + bias_ur)));
#pragma unroll
            for (int f = 0; f < 8; ++f)
                acc_c = __builtin_amdgcn_mfma_f32_16x16x32_f16(axx[f], W3[f], acc_c, 0, 0, 0);
        }
        bar_wait(flags, 32, 2u * (unsigned)t + 1u);

        // ---------------- Phase B ----------------
        const bool lastt = (t == TT - 1);
        const int tn  = lastt ? t : (t + 1);
        const int txn = dir ? (TT - 1 - tn) : tn;
        floatx4 nacc = {0.f, 0.f, 0.f, 0.f};
        if (wave < 2) {
            // stage rh(t) -> LDS (128 threads, 8x16B each)
            uintx4 sr[8];
#pragma unroll
            for (int rr = 0; rr < 8; ++rr)
                sr[rr] = ld16c(rhb + ((long)rr * 128 + tid) * 8);
            asm volatile("s_waitcnt vmcnt(0)" ::: "memory");
            __builtin_amdgcn_sched_barrier(0);
#pragma unroll
            for (int rr = 0; rr < 8; ++rr)
                *(uintx4*)&lds_rst[((long)rr * 128 + tid) * 8] = sr[rr];
        } else {
            // window: x(t+1) frags + r x-part for t+1
            const __half* xr = x16 + ((long)txn * BB + b0 + n) * DD + koff;
#pragma unroll
            for (int f = 0; f < 8; ++f) axx[f] = *(const half8*)(xr + f * 32);
#pragma unroll
            for (int f = 0; f < 8; ++f)
                nacc = __builtin_amdgcn_mfma_f32_16x16x32_f16(axx[f], WA[f], nacc, 0, 0, 0);
        }
        barrier_lgkm();

        if (wave < 2) {
            floatx4 c1 = {0.f, 0.f, 0.f, 0.f};
            half8 arh[8];
#pragma unroll
            for (int f = 0; f < 8; ++f)
                arh[f] = *(const half8*)&lds_rst[((f * 4 + quad) * 16 + n) * 8];
#pragma unroll
            for (int f = 0; f < 8; ++f)
                acc_c = __builtin_amdgcn_mfma_f32_16x16x32_f16(arh[f], WC[f], acc_c, 0, 0, 0);
#pragma unroll
            for (int f = 0; f < 8; ++f)
                arh[f] = *(const half8*)&lds_rst[(((8 + f) * 4 + quad) * 16 + n) * 8];
#pragma unroll
            for (int f = 0; f < 8; ++f)
                c1 = __builtin_amdgcn_mfma_f32_16x16x32_f16(arh[f], WC[8 + f], c1, 0, 0, 0);
            acc_c = acc_c + c1;

#pragma unroll
            for (int i = 0; i < 4; ++i) {
                float pre = acc_c[i] + bias_c;
                pre = fminf(fmaxf(pre, -15.0f), 15.0f);
                const float e2 = __expf(2.0f * pre);
                const float hh = (e2 - 1.0f) / (e2 + 1.0f);
                const float hn = (1.0f - u_keep[i]) * h_own[i] + u_keep[i] * hh;
                h_own[i] = hn;
                lds_hprev[quad * 4 + i][wave * 16 + n] = (__half)hn;
                lds_out[quad * 4 + i][wave * 16 + n] = hn;
            }
            acc_c = (floatx4){0.f, 0.f, 0.f, 0.f};
            asm volatile("s_waitcnt lgkmcnt(0)" ::: "memory");
            __builtin_amdgcn_sched_barrier(0);
            if (lane < 32) {
                const int kcl = lane >> 4, b = lane & 15;
                const u64* src = (const u64*)&lds_hprev[b][wave * 16 + kcl * 8];
                u64* dst = (u64*)(h16 + ((long)(((t + 1) & 1) * 2 + dir) * 4 + gb) * 8192
                                      + ((long)(sb * 4 + wave * 2 + kcl) * 16 + b) * 8);
                __hip_atomic_store(dst,     src[0], __ATOMIC_RELAXED, __HIP_MEMORY_SCOPE_AGENT);
                __hip_atomic_store(dst + 1, src[1], __ATOMIC_RELAXED, __HIP_MEMORY_SCOPE_AGENT);
            }
            asm volatile("s_waitcnt vmcnt(0)" ::: "memory");
            if (lane == 0)
                __hip_atomic_store(&flags[sb * 2 + wave], 2u * (unsigned)t + 2u,
                                   __ATOMIC_RELAXED, __HIP_MEMORY_SCOPE_AGENT);
            // window: x(t+1) frags + u x-part for t+1
            const __half* xr = x16 + ((long)txn * BB + b0 + n) * DD + koff;
#pragma unroll
            for (int f = 0; f < 8; ++f) axx[f] = *(const half8*)(xr + f * 32);
#pragma unroll
            for (int f = 0; f < 8; ++f)
                nacc = __builtin_amdgcn_mfma_f32_16x16x32_f16(axx[f], WA[f], nacc, 0, 0, 0);
        }
        bar_wait(flags, 0, 2u * (unsigned)t + 2u);
        acc_ur = nacc;
    }

    // final out store for t = TT-1 (bar_wait's barrier ordered lds_out writes)
    if (tid < 128) {
        const int b = tid >> 3, cc = tid & 7;
        *(floatx4*)&out[((long)(b0 + b) * TT + (TT - 1)) * (2 * UU) + dir * UU + j0 + cc * 4]
            = *(const floatx4*)&lds_out[b][cc * 4];
    }
}

extern "C" void kernel_launch(void* const* d_in, const int* in_sizes, int n_in,
                              void* d_out, int out_size, void* d_ws, size_t ws_size,
                              hipStream_t stream) {
    const float* x    = (const float*)d_in[0];
    const float* Wx_f = (const float*)d_in[1];
    const float* Wh_f = (const float*)d_in[2];
    const float* b_f  = (const float*)d_in[3];
    const float* Wx_b = (const float*)d_in[4];
    const float* Wh_b = (const float*)d_in[5];
    const float* b_b  = (const float*)d_in[6];
    float* out = (float*)d_out;

    char* ws = (char*)d_ws;
    // ws layout: x16 16.78MB | h16 256KB | rh16 128KB | bars 4KB
    __half* x16    = (__half*)ws;
    __half* h16    = (__half*)(ws + (size_t)TT * BB * DD * 2);
    __half* rh16   = (__half*)(ws + (size_t)TT * BB * DD * 2 + (size_t)2 * 2 * BB * UU * 2);
    unsigned* bars = (unsigned*)(ws + (size_t)TT * BB * DD * 2 + (size_t)2 * 2 * BB * UU * 2
                                    + (size_t)2 * BB * UU * 2);

    const long nsetup = (long)TT * BB * DD;
    bigru_setup<<<(int)((nsetup + 255) / 256), 256, 0, stream>>>(x, x16, h16, bars);
    bigru_persistent<<<128, 256, 0, stream>>>(x16, Wx_f, Wh_f, b_f, Wx_b, Wh_b, b_b,
                                              h16, rh16, bars, out);
}